// Round 1
// baseline (593.714 us; speedup 1.0000x reference)
//
#include <hip/hip_runtime.h>
#include <math.h>

#define BATCH 8
#define CINCH 256
#define CMID  128
#define NPIX  4096   // H*W = 64*64
#define MPIX  1024   // 32*32

// ---------------------------------------------------------------------------
// Tiled fp32 conv1x1 GEMM: out = W[Cout,Cin] @ in[b][Cin][L] + bias
// OUT_LC=true  -> out[b][L][Cout]   (theta / phiT / giT layouts)
// OUT_LC=false -> out[b][Cout][L]   (final conv, optional residual add)
// Block: 256 threads; tile: 32 L x 128 Cout; 4x4 register blocking.
// ---------------------------------------------------------------------------
template<int TCIN, bool OUT_LC, bool RES>
__global__ __launch_bounds__(256)
void conv1x1_k(const float* __restrict__ in, const float* __restrict__ w,
               const float* __restrict__ bias, const float* __restrict__ res,
               float* __restrict__ out, int L, int Cout)
{
    __shared__ float xs[32][33];    // [Cin-chunk][L-tile]
    __shared__ float wsm[128][33];  // [Cout-tile][Cin-chunk]
    const int b   = blockIdx.z;
    const int L0  = blockIdx.x * 32;
    const int Co0 = blockIdx.y * 128;
    const int t   = threadIdx.x;
    const int tn  = t & 7;    // L subgroup (4 each)
    const int tc  = t >> 3;   // Cout subgroup (4 each), 0..31

    float acc[4][4];
#pragma unroll
    for (int i = 0; i < 4; ++i)
#pragma unroll
        for (int k = 0; k < 4; ++k) acc[i][k] = 0.f;

    const float* inb = in + (size_t)b * TCIN * L + L0;

    for (int C0 = 0; C0 < TCIN; C0 += 32) {
#pragma unroll
        for (int r = 0; r < 4; ++r) {
            int idx = t + r * 256;
            xs[idx >> 5][idx & 31] = inb[(size_t)(C0 + (idx >> 5)) * L + (idx & 31)];
        }
#pragma unroll
        for (int r = 0; r < 16; ++r) {
            int idx = t + r * 256;
            wsm[idx >> 5][idx & 31] = w[(size_t)(Co0 + (idx >> 5)) * TCIN + C0 + (idx & 31)];
        }
        __syncthreads();
#pragma unroll
        for (int i = 0; i < 32; ++i) {
            float xv[4], wv[4];
#pragma unroll
            for (int ii = 0; ii < 4; ++ii) xv[ii] = xs[i][tn * 4 + ii];
#pragma unroll
            for (int k = 0; k < 4; ++k) wv[k] = wsm[tc * 4 + k][i];
#pragma unroll
            for (int ii = 0; ii < 4; ++ii)
#pragma unroll
                for (int k = 0; k < 4; ++k) acc[ii][k] += xv[ii] * wv[k];
        }
        __syncthreads();
    }

#pragma unroll
    for (int k = 0; k < 4; ++k) {
        int cc = Co0 + tc * 4 + k;
        float bv = bias[cc];
#pragma unroll
        for (int ii = 0; ii < 4; ++ii) {
            int l = L0 + tn * 4 + ii;
            float v = acc[ii][k] + bv;
            if (OUT_LC) {
                out[((size_t)b * L + l) * Cout + cc] = v;
            } else {
                size_t o = ((size_t)b * Cout + cc) * L + l;
                if (RES) v += res[o];
                out[o] = v;
            }
        }
    }
}

// ---------------------------------------------------------------------------
// MaxPool2d(2,2): x[B,256,64,64] -> xp[B,256,32,32]  (as [B,256,1024])
// ---------------------------------------------------------------------------
__global__ __launch_bounds__(256)
void maxpool_k(const float* __restrict__ x, float* __restrict__ xp)
{
    int idx = blockIdx.x * 256 + threadIdx.x;       // B*256*1024 total
    int m  = idx & 1023;
    int bc = idx >> 10;
    int wp = m & 31, hp = m >> 5;
    const float* px = x + (size_t)bc * 4096 + (size_t)(hp * 2) * 64 + wp * 2;
    float v = fmaxf(fmaxf(px[0], px[1]), fmaxf(px[64], px[65]));
    xp[idx] = v;
}

// ---------------------------------------------------------------------------
// Attention: per block, 16 query rows of one batch.
//  scores sc[16][1024] in LDS (fp32, exact softmax), then PV with coalesced
//  gi reads. theta [B,N,128], phiT/giT [B,M,128], m2 [B,N,128].
// ---------------------------------------------------------------------------
__global__ __launch_bounds__(256)
void attn_k(const float* __restrict__ theta, const float* __restrict__ phiT,
            const float* __restrict__ giT, float* __restrict__ m2)
{
    __shared__ float th[16][128];
    __shared__ float sc[16][1024];
    const int b  = blockIdx.y;
    const int n0 = blockIdx.x * 16;
    const int t  = threadIdx.x;

    const float* thg = theta + ((size_t)b * NPIX + n0) * CMID;
#pragma unroll
    for (int r = 0; r < 8; ++r) {
        int idx = t + r * 256;
        th[idx >> 7][idx & 127] = thg[idx];
    }
    __syncthreads();

    // ---- QK^T: each thread does 4 keys x 16 query rows, phi row read once
    const float* phb = phiT + (size_t)b * MPIX * CMID;
    for (int s = 0; s < 4; ++s) {
        int m = s * 256 + t;
        const float4* ph4 = (const float4*)(phb + (size_t)m * CMID);
        float acc[16];
#pragma unroll
        for (int nl = 0; nl < 16; ++nl) acc[nl] = 0.f;
        for (int q = 0; q < 32; ++q) {
            float4 pv = ph4[q];
#pragma unroll
            for (int nl = 0; nl < 16; ++nl) {
                const float4 tv = ((const float4*)th[nl])[q];
                acc[nl] += pv.x * tv.x + pv.y * tv.y + pv.z * tv.z + pv.w * tv.w;
            }
        }
#pragma unroll
        for (int nl = 0; nl < 16; ++nl) sc[nl][m] = acc[nl];
    }
    __syncthreads();

    // ---- exact softmax per row (wave handles 4 rows)
    {
        int wv = t >> 6, ln = t & 63;
        for (int r = 0; r < 4; ++r) {
            int row = wv * 4 + r;
            float mx = -1e30f;
            for (int q = ln; q < 1024; q += 64) mx = fmaxf(mx, sc[row][q]);
#pragma unroll
            for (int off = 32; off; off >>= 1) mx = fmaxf(mx, __shfl_xor(mx, off));
            float sm = 0.f;
            for (int q = ln; q < 1024; q += 64) {
                float e = __expf(sc[row][q] - mx);
                sc[row][q] = e;
                sm += e;
            }
#pragma unroll
            for (int off = 32; off; off >>= 1) sm += __shfl_xor(sm, off);
            float inv = 1.f / sm;
            for (int q = ln; q < 1024; q += 64) sc[row][q] *= inv;
        }
    }
    __syncthreads();

    // ---- PV: thread owns (cc, m-half); gi reads coalesced across cc
    const float* gib = giT + (size_t)b * MPIX * CMID;
    const int cc = t & 127;
    const int g  = t >> 7;
    float acc[16];
#pragma unroll
    for (int nl = 0; nl < 16; ++nl) acc[nl] = 0.f;
    for (int m = g * 512; m < g * 512 + 512; ++m) {
        float gv = gib[(size_t)m * CMID + cc];
#pragma unroll
        for (int nl = 0; nl < 16; ++nl) acc[nl] += sc[nl][m] * gv;
    }
    __syncthreads();
    if (g == 0) {
#pragma unroll
        for (int nl = 0; nl < 16; ++nl) th[nl][cc] = acc[nl];
    }
    __syncthreads();
    if (g == 1) {
#pragma unroll
        for (int nl = 0; nl < 16; ++nl) {
            m2[((size_t)b * NPIX + n0 + nl) * CMID + cc] = acc[nl] + th[nl][cc];
        }
    }
}

extern "C" void kernel_launch(void* const* d_in, const int* in_sizes, int n_in,
                              void* d_out, int out_size, void* d_ws, size_t ws_size,
                              hipStream_t stream)
{
    const float* x       = (const float*)d_in[0];
    const float* theta_w = (const float*)d_in[1];
    const float* theta_b = (const float*)d_in[2];
    const float* phi_w   = (const float*)d_in[3];
    const float* phi_b   = (const float*)d_in[4];
    const float* g_w     = (const float*)d_in[5];
    const float* g_b     = (const float*)d_in[6];
    const float* wz_w    = (const float*)d_in[7];
    const float* wz_b    = (const float*)d_in[8];
    float* out = (float*)d_out;

    float* ws    = (float*)d_ws;
    float* theta = ws;                              // [B,4096,128]  4194304
    float* xp    = theta + (size_t)4194304;         // [B,256,1024]  2097152
    float* phiT  = xp    + (size_t)2097152;         // [B,1024,128]  1048576
    float* giT   = phiT  + (size_t)1048576;         // [B,1024,128]  1048576
    float* m2    = giT   + (size_t)1048576;         // [B,4096,128]  4194304
    // m2 as flat [B, N*c] is byte-identical to m3 [B, c, 4096] (torch .view)

    // theta = conv1x1(x) -> [B, N, c]
    conv1x1_k<CINCH, true, false><<<dim3(NPIX / 32, 1, BATCH), 256, 0, stream>>>(
        x, theta_w, theta_b, nullptr, theta, NPIX, CMID);

    // maxpool
    maxpool_k<<<dim3(BATCH * CINCH * MPIX / 256), 256, 0, stream>>>(x, xp);

    // phiT / giT = conv1x1(xp) -> [B, M, c]
    conv1x1_k<CINCH, true, false><<<dim3(MPIX / 32, 1, BATCH), 256, 0, stream>>>(
        xp, phi_w, phi_b, nullptr, phiT, MPIX, CMID);
    conv1x1_k<CINCH, true, false><<<dim3(MPIX / 32, 1, BATCH), 256, 0, stream>>>(
        xp, g_w, g_b, nullptr, giT, MPIX, CMID);

    // attention -> m2 [B, N, c]
    attn_k<<<dim3(NPIX / 16, BATCH), 256, 0, stream>>>(theta, phiT, giT, m2);

    // out = conv1x1(m3) + x, m3 = m2 viewed as [B, c, 4096]
    conv1x1_k<CMID, false, true><<<dim3(NPIX / 32, CINCH / 128, BATCH), 256, 0, stream>>>(
        m2, wz_w, wz_b, x, out, NPIX, CINCH);
}

// Round 2
// 204.313 us; speedup vs baseline: 2.9059x; 2.9059x over previous
//
#include <hip/hip_runtime.h>
#include <math.h>

#define BATCH 8
#define CINCH 256
#define CMID  128
#define NPIX  4096   // H*W = 64*64
#define MPIX  1024   // 32*32

typedef __attribute__((ext_vector_type(8))) short bf16x8;
typedef __attribute__((ext_vector_type(4))) float f32x4;

static __device__ __forceinline__ short f2bf(float f) {
    unsigned u = __float_as_uint(f);
    u = (u + 0x7fffu + ((u >> 16) & 1u)) >> 16;   // RNE bf16
    return (short)u;
}

// ---------------------------------------------------------------------------
// Tiled fp32 conv1x1 GEMM: out = W[Cout,Cin] @ in[b][Cin][L] + bias
// OUT_LC=true  -> out[b][L][Cout]; OUT_LC=false -> out[b][Cout][L]
// BF16OUT selects bf16 vs fp32 output. RES adds residual (fp32 path only).
// ---------------------------------------------------------------------------
template<int TCIN, bool OUT_LC, bool RES, bool BF16OUT>
__global__ __launch_bounds__(256)
void conv1x1_k(const float* __restrict__ in, const float* __restrict__ w,
               const float* __restrict__ bias, const float* __restrict__ res,
               void* __restrict__ outp, int L, int Cout)
{
    __shared__ float xs[32][33];    // [Cin-chunk][L-tile]
    __shared__ float wsm[128][33];  // [Cout-tile][Cin-chunk]
    const int b   = blockIdx.z;
    const int L0  = blockIdx.x * 32;
    const int Co0 = blockIdx.y * 128;
    const int t   = threadIdx.x;
    const int tn  = t & 7;
    const int tc  = t >> 3;

    float acc[4][4];
#pragma unroll
    for (int i = 0; i < 4; ++i)
#pragma unroll
        for (int k = 0; k < 4; ++k) acc[i][k] = 0.f;

    const float* inb = in + (size_t)b * TCIN * L + L0;

    for (int C0 = 0; C0 < TCIN; C0 += 32) {
#pragma unroll
        for (int r = 0; r < 4; ++r) {
            int idx = t + r * 256;
            xs[idx >> 5][idx & 31] = inb[(size_t)(C0 + (idx >> 5)) * L + (idx & 31)];
        }
#pragma unroll
        for (int r = 0; r < 16; ++r) {
            int idx = t + r * 256;
            wsm[idx >> 5][idx & 31] = w[(size_t)(Co0 + (idx >> 5)) * TCIN + C0 + (idx & 31)];
        }
        __syncthreads();
#pragma unroll
        for (int i = 0; i < 32; ++i) {
            float xv[4], wv[4];
#pragma unroll
            for (int ii = 0; ii < 4; ++ii) xv[ii] = xs[i][tn * 4 + ii];
#pragma unroll
            for (int k = 0; k < 4; ++k) wv[k] = wsm[tc * 4 + k][i];
#pragma unroll
            for (int ii = 0; ii < 4; ++ii)
#pragma unroll
                for (int k = 0; k < 4; ++k) acc[ii][k] += xv[ii] * wv[k];
        }
        __syncthreads();
    }

#pragma unroll
    for (int k = 0; k < 4; ++k) {
        int cc = Co0 + tc * 4 + k;
        float bv = bias[cc];
#pragma unroll
        for (int ii = 0; ii < 4; ++ii) {
            int l = L0 + tn * 4 + ii;
            float v = acc[ii][k] + bv;
            size_t o;
            if (OUT_LC) o = ((size_t)b * L + l) * Cout + cc;
            else        o = ((size_t)b * Cout + cc) * L + l;
            if (!OUT_LC && RES) v += res[o];
            if (BF16OUT) ((short*)outp)[o] = f2bf(v);
            else         ((float*)outp)[o] = v;
        }
    }
}

// ---------------------------------------------------------------------------
// MaxPool2d(2,2): x[B,256,64,64] -> xp[B,256,32,32]
// ---------------------------------------------------------------------------
__global__ __launch_bounds__(256)
void maxpool_k(const float* __restrict__ x, float* __restrict__ xp)
{
    int idx = blockIdx.x * 256 + threadIdx.x;
    int m  = idx & 1023;
    int bc = idx >> 10;
    int wp = m & 31, hp = m >> 5;
    const float* px = x + (size_t)bc * 4096 + (size_t)(hp * 2) * 64 + wp * 2;
    xp[idx] = fmaxf(fmaxf(px[0], px[1]), fmaxf(px[64], px[65]));
}

// ---------------------------------------------------------------------------
// MFMA attention. theta [B,N,128] bf16, phi [B,M,128] bf16, G [B,128,M] bf16.
// Block = 4 independent waves, each owns 32 q-rows. Flash-style over m-chunks
// of 32 with defer-max online softmax; P re-layout via per-wave padded LDS.
// Output m2 [B,N,128] fp32 (byte-identical to m3 [B,128,4096] view).
// ---------------------------------------------------------------------------
__global__ __launch_bounds__(256)
void attn_mfma_k(const short* __restrict__ theta, const short* __restrict__ phi,
                 const short* __restrict__ G, float* __restrict__ m2)
{
    __shared__ short plds[4][32 * 40];   // per-wave P staging, stride 40 (pad)
    const int t  = threadIdx.x;
    const int w  = t >> 6;
    const int l  = t & 63;
    const int lr = l & 15;
    const int lg = l >> 4;
    const int b  = blockIdx.y;
    const int n0 = blockIdx.x * 128 + w * 32;

    const short* thb = theta + ((size_t)b * NPIX + n0) * CMID;
    const short* phb = phi   + (size_t)b * MPIX * CMID;
    const short* Gb  = G     + (size_t)b * CMID * MPIX;
    short* pl = &plds[w][0];

    // theta A-frags: row n = nt*16+lr, k = kt*32 + lg*8 + j
    bf16x8 afr[2][4];
#pragma unroll
    for (int nt = 0; nt < 2; ++nt)
#pragma unroll
        for (int kt = 0; kt < 4; ++kt)
            afr[nt][kt] = *(const bf16x8*)(thb + (size_t)(nt * 16 + lr) * CMID + kt * 32 + lg * 8);

    f32x4 o[2][8];
    float rm[2][4], ps[2][4];
#pragma unroll
    for (int nt = 0; nt < 2; ++nt) {
#pragma unroll
        for (int dt = 0; dt < 8; ++dt)
#pragma unroll
            for (int e = 0; e < 4; ++e) o[nt][dt][e] = 0.f;
#pragma unroll
        for (int r = 0; r < 4; ++r) { rm[nt][r] = -1e30f; ps[nt][r] = 0.f; }
    }

    for (int mc = 0; mc < MPIX; mc += 32) {
        // ---- QK^T: S[n, m] rows from theta (A), cols from phi (B)
        f32x4 s[2][2];
#pragma unroll
        for (int nt = 0; nt < 2; ++nt)
#pragma unroll
            for (int mt = 0; mt < 2; ++mt)
#pragma unroll
                for (int e = 0; e < 4; ++e) s[nt][mt][e] = 0.f;
#pragma unroll
        for (int kt = 0; kt < 4; ++kt) {
            bf16x8 b0 = *(const bf16x8*)(phb + (size_t)(mc + lr) * CMID + kt * 32 + lg * 8);
            bf16x8 b1 = *(const bf16x8*)(phb + (size_t)(mc + 16 + lr) * CMID + kt * 32 + lg * 8);
#pragma unroll
            for (int nt = 0; nt < 2; ++nt) {
                s[nt][0] = __builtin_amdgcn_mfma_f32_16x16x32_bf16(afr[nt][kt], b0, s[nt][0], 0, 0, 0);
                s[nt][1] = __builtin_amdgcn_mfma_f32_16x16x32_bf16(afr[nt][kt], b1, s[nt][1], 0, 0, 0);
            }
        }

        // ---- V fragments for this chunk (issue early; used after softmax)
        bf16x8 gf[8];
#pragma unroll
        for (int dt = 0; dt < 8; ++dt)
            gf[dt] = *(const bf16x8*)(Gb + (size_t)(dt * 16 + lr) * MPIX + mc + lg * 8);

        // ---- defer-max: only reduce+rescale if some score exceeds rm+8
        int big = 0;
#pragma unroll
        for (int nt = 0; nt < 2; ++nt)
#pragma unroll
            for (int mt = 0; mt < 2; ++mt)
#pragma unroll
                for (int r = 0; r < 4; ++r)
                    big |= (s[nt][mt][r] > rm[nt][r] + 8.f) ? 1 : 0;
        if (__any(big)) {
#pragma unroll
            for (int nt = 0; nt < 2; ++nt)
#pragma unroll
                for (int r = 0; r < 4; ++r) {
                    float cm = fmaxf(s[nt][0][r], s[nt][1][r]);
#pragma unroll
                    for (int off = 8; off >= 1; off >>= 1)
                        cm = fmaxf(cm, __shfl_xor(cm, off));
                    float nm = fmaxf(rm[nt][r], cm);
                    float sc = __expf(rm[nt][r] - nm);
                    ps[nt][r] *= sc;
                    rm[nt][r] = nm;
#pragma unroll
                    for (int dt = 0; dt < 8; ++dt) o[nt][dt][r] *= sc;
                }
        }

        // ---- P = exp(S - rm): per-lane partial sums + bf16 store to LDS
#pragma unroll
        for (int nt = 0; nt < 2; ++nt)
#pragma unroll
            for (int mt = 0; mt < 2; ++mt)
#pragma unroll
                for (int r = 0; r < 4; ++r) {
                    float p = __expf(s[nt][mt][r] - rm[nt][r]);
                    ps[nt][r] += p;
                    pl[(nt * 16 + lg * 4 + r) * 40 + mt * 16 + lr] = f2bf(p);
                }

        // ---- PV: A = P from LDS (row n = lr, k = m), B = G frags
#pragma unroll
        for (int nt = 0; nt < 2; ++nt) {
            bf16x8 pa = *(const bf16x8*)(pl + (size_t)(nt * 16 + lr) * 40 + lg * 8);
#pragma unroll
            for (int dt = 0; dt < 8; ++dt)
                o[nt][dt] = __builtin_amdgcn_mfma_f32_16x16x32_bf16(pa, gf[dt], o[nt][dt], 0, 0, 0);
        }
    }

    // ---- finalize: reduce per-lane partial sums over the 16-lane group, store
#pragma unroll
    for (int nt = 0; nt < 2; ++nt)
#pragma unroll
        for (int r = 0; r < 4; ++r) {
            float sTot = ps[nt][r];
#pragma unroll
            for (int off = 8; off >= 1; off >>= 1) sTot += __shfl_xor(sTot, off);
            float inv = 1.f / sTot;
#pragma unroll
            for (int dt = 0; dt < 8; ++dt) {
                m2[((size_t)b * NPIX + n0 + nt * 16 + lg * 4 + r) * CMID + dt * 16 + lr]
                    = o[nt][dt][r] * inv;
            }
        }
}

extern "C" void kernel_launch(void* const* d_in, const int* in_sizes, int n_in,
                              void* d_out, int out_size, void* d_ws, size_t ws_size,
                              hipStream_t stream)
{
    const float* x       = (const float*)d_in[0];
    const float* theta_w = (const float*)d_in[1];
    const float* theta_b = (const float*)d_in[2];
    const float* phi_w   = (const float*)d_in[3];
    const float* phi_b   = (const float*)d_in[4];
    const float* g_w     = (const float*)d_in[5];
    const float* g_b     = (const float*)d_in[6];
    const float* wz_w    = (const float*)d_in[7];
    const float* wz_b    = (const float*)d_in[8];
    float* out = (float*)d_out;

    float* ws      = (float*)d_ws;
    float* xp      = ws;                          // [B,256,1024]   2097152 f32
    float* m2      = xp + (size_t)2097152;        // [B,4096,128]   4194304 f32
    short* theta_h = (short*)(m2 + (size_t)4194304); // [B,4096,128] bf16
    short* phi_h   = theta_h + (size_t)4194304;   // [B,1024,128] bf16
    short* G_h     = phi_h + (size_t)1048576;     // [B,128,1024] bf16

    // theta = conv1x1(x) -> bf16 [B, N, c]
    conv1x1_k<CINCH, true, false, true><<<dim3(NPIX / 32, 1, BATCH), 256, 0, stream>>>(
        x, theta_w, theta_b, nullptr, theta_h, NPIX, CMID);

    // maxpool
    maxpool_k<<<dim3(BATCH * CINCH * MPIX / 256), 256, 0, stream>>>(x, xp);

    // phi -> bf16 [B, M, c];  G -> bf16 [B, c, M] (channel-major for PV B-frags)
    conv1x1_k<CINCH, true, false, true><<<dim3(MPIX / 32, 1, BATCH), 256, 0, stream>>>(
        xp, phi_w, phi_b, nullptr, phi_h, MPIX, CMID);
    conv1x1_k<CINCH, false, false, true><<<dim3(MPIX / 32, 1, BATCH), 256, 0, stream>>>(
        xp, g_w, g_b, nullptr, G_h, MPIX, CMID);

    // attention -> m2 [B, N, c] fp32
    attn_mfma_k<<<dim3(NPIX / 128, BATCH), 256, 0, stream>>>(theta_h, phi_h, G_h, m2);

    // out = conv1x1(m3) + x, m3 = m2 viewed as [B, c, 4096]
    conv1x1_k<CMID, false, true, false><<<dim3(NPIX / 32, CINCH / 128, BATCH), 256, 0, stream>>>(
        m2, wz_w, wz_b, x, out, NPIX, CINCH);
}

// Round 3
// 187.317 us; speedup vs baseline: 3.1696x; 1.0907x over previous
//
#include <hip/hip_runtime.h>
#include <math.h>

#define BATCH 8
#define CINCH 256
#define CMID  128
#define NPIX  4096   // 64*64
#define MPIX  1024   // 32*32

typedef __attribute__((ext_vector_type(8))) short bf16x8;
typedef __attribute__((ext_vector_type(4))) short s16x4;
typedef __attribute__((ext_vector_type(4))) float f32x4;

static __device__ __forceinline__ short f2bf(float f) {
    unsigned u = __float_as_uint(f);
    u = (u + 0x7fffu + ((u >> 16) & 1u)) >> 16;   // RNE bf16
    return (short)u;
}

static __device__ __forceinline__ void gl16(const void* g, void* l) {
    __builtin_amdgcn_global_load_lds(
        (const __attribute__((address_space(1))) void*)g,
        (__attribute__((address_space(3))) void*)l, 16, 0, 0);
}

// ---------------------------------------------------------------------------
// conv1x1 GEMM: out = W[Cout,Cin] @ in[b][Cin][L] + bias.  LAYOUT:
//  0: fp32 out[b][Cout][L] + residual   (final conv)
//  1: bf16 out[b][L][128]               (theta, linear)
//  2: bf16 phi, chunk-swizzled:  [b][chunk32][ (r*256+ch*2)^((r&7)<<4) ]
//  3: bf16 G, granule-permuted:  [b][chunk32][ p(ch,q)*16 + j*2 ],
//     p(ch,q) = (ch*4+q)^(ch&7)
// ---------------------------------------------------------------------------
template<int TCIN, int LAYOUT>
__global__ __launch_bounds__(256)
void conv1x1_k(const float* __restrict__ in, const float* __restrict__ w,
               const float* __restrict__ bias, const float* __restrict__ res,
               void* __restrict__ outp, int L, int Cout)
{
    __shared__ float xs[32][33];
    __shared__ float wsm[128][33];
    const int b   = blockIdx.z;
    const int L0  = blockIdx.x * 32;
    const int Co0 = blockIdx.y * 128;
    const int t   = threadIdx.x;
    const int tn  = t & 7;
    const int tc  = t >> 3;

    float acc[4][4];
#pragma unroll
    for (int i = 0; i < 4; ++i)
#pragma unroll
        for (int k = 0; k < 4; ++k) acc[i][k] = 0.f;

    const float* inb = in + (size_t)b * TCIN * L + L0;

    for (int C0 = 0; C0 < TCIN; C0 += 32) {
#pragma unroll
        for (int r = 0; r < 4; ++r) {
            int idx = t + r * 256;
            xs[idx >> 5][idx & 31] = inb[(size_t)(C0 + (idx >> 5)) * L + (idx & 31)];
        }
#pragma unroll
        for (int r = 0; r < 16; ++r) {
            int idx = t + r * 256;
            wsm[idx >> 5][idx & 31] = w[(size_t)(Co0 + (idx >> 5)) * TCIN + C0 + (idx & 31)];
        }
        __syncthreads();
#pragma unroll
        for (int i = 0; i < 32; ++i) {
            float xv[4], wv[4];
#pragma unroll
            for (int ii = 0; ii < 4; ++ii) xv[ii] = xs[i][tn * 4 + ii];
#pragma unroll
            for (int k = 0; k < 4; ++k) wv[k] = wsm[tc * 4 + k][i];
#pragma unroll
            for (int ii = 0; ii < 4; ++ii)
#pragma unroll
                for (int k = 0; k < 4; ++k) acc[ii][k] += xv[ii] * wv[k];
        }
        __syncthreads();
    }

    if (LAYOUT == 0) {
        float* of = (float*)outp;
#pragma unroll
        for (int k = 0; k < 4; ++k) {
            int cc = Co0 + tc * 4 + k;
            float bv = bias[cc];
            size_t o = ((size_t)b * Cout + cc) * L + L0 + tn * 4;
            f32x4 rv = *(const f32x4*)(res + o);
            f32x4 v = { acc[0][k] + bv + rv[0], acc[1][k] + bv + rv[1],
                        acc[2][k] + bv + rv[2], acc[3][k] + bv + rv[3] };
            *(f32x4*)(of + o) = v;
        }
    } else if (LAYOUT == 1) {
        float b0 = bias[tc * 4], b1 = bias[tc * 4 + 1], b2 = bias[tc * 4 + 2], b3 = bias[tc * 4 + 3];
#pragma unroll
        for (int ii = 0; ii < 4; ++ii) {
            int l = L0 + tn * 4 + ii;
            s16x4 sv = { f2bf(acc[ii][0] + b0), f2bf(acc[ii][1] + b1),
                         f2bf(acc[ii][2] + b2), f2bf(acc[ii][3] + b3) };
            *(s16x4*)((short*)outp + ((size_t)b * L + l) * 128 + tc * 4) = sv;
        }
    } else if (LAYOUT == 2) {
        float b0 = bias[tc * 4], b1 = bias[tc * 4 + 1], b2 = bias[tc * 4 + 2], b3 = bias[tc * 4 + 3];
#pragma unroll
        for (int ii = 0; ii < 4; ++ii) {
            int l = L0 + tn * 4 + ii;
            int r = l & 31, chunk = l >> 5;
            s16x4 sv = { f2bf(acc[ii][0] + b0), f2bf(acc[ii][1] + b1),
                         f2bf(acc[ii][2] + b2), f2bf(acc[ii][3] + b3) };
            size_t off = ((size_t)b * 32 + chunk) * 8192
                       + ((r * 256 + tc * 8) ^ ((r & 7) << 4));
            *(s16x4*)((char*)outp + off) = sv;
        }
    } else {  // LAYOUT 3: G
        int chunk = L0 >> 5;
        int q = tn >> 1;
#pragma unroll
        for (int k = 0; k < 4; ++k) {
            int ch = tc * 4 + k;
            float bv = bias[ch];
            int p = ((ch * 4 + q) ^ (ch & 7));
            s16x4 sv = { f2bf(acc[0][k] + bv), f2bf(acc[1][k] + bv),
                         f2bf(acc[2][k] + bv), f2bf(acc[3][k] + bv) };
            *(s16x4*)((short*)outp + (((size_t)b * 32 + chunk) * 512 + p) * 8 + (tn & 1) * 4) = sv;
        }
    }
}

// ---------------------------------------------------------------------------
// MaxPool2d(2,2)
// ---------------------------------------------------------------------------
__global__ __launch_bounds__(256)
void maxpool_k(const float* __restrict__ x, float* __restrict__ xp)
{
    int idx = blockIdx.x * 256 + threadIdx.x;
    int m  = idx & 1023;
    int bc = idx >> 10;
    int wp = m & 31, hp = m >> 5;
    const float* px = x + (size_t)bc * 4096 + (size_t)(hp * 2) * 64 + wp * 2;
    xp[idx] = fmaxf(fmaxf(px[0], px[1]), fmaxf(px[64], px[65]));
}

// ---------------------------------------------------------------------------
// MFMA attention, double-buffered LDS staging of phi+G shared by 4 waves.
// theta [B,N,128] bf16; phi_sw/G_sw in attn-native swizzled chunk layouts.
// ---------------------------------------------------------------------------
__global__ __launch_bounds__(256)
void attn_v3(const short* __restrict__ theta, const short* __restrict__ phi_sw,
             const short* __restrict__ G_sw, float* __restrict__ m2)
{
    __shared__ short phiL[2][4096];   // 2 x 8KB
    __shared__ short gL[2][4096];     // 2 x 8KB
    __shared__ short pl4[4][32 * 40]; // per-wave P slab (padded stride 40)

    const int t  = threadIdx.x;
    const int w  = t >> 6;
    const int l  = t & 63;
    const int lr = l & 15;
    const int lg = l >> 4;
    const int bid  = blockIdx.x;
    const int b    = bid & 7;       // batch -> XCD (i%8 heuristic)
    const int tile = bid >> 3;
    const int n0   = tile * 128 + w * 32;

    const short* thb = theta + ((size_t)b * NPIX + n0) * CMID;
    const char*  phC = (const char*)phi_sw + (size_t)b * 32 * 8192;
    const char*  gC  = (const char*)G_sw  + (size_t)b * 32 * 8192;
    short* pl = &pl4[w][0];

    // constant per-lane LDS read offsets
    int phOff[4][2];
#pragma unroll
    for (int kt = 0; kt < 4; ++kt)
#pragma unroll
        for (int mt = 0; mt < 2; ++mt) {
            int r = mt * 16 + lr;
            phOff[kt][mt] = (r * 256 + kt * 64 + lg * 16) ^ ((lr & 7) << 4);
        }
    int gOff[8];
#pragma unroll
    for (int dt = 0; dt < 8; ++dt) {
        int ch = dt * 16 + lr;
        gOff[dt] = (((ch * 4 + lg) ^ (ch & 7)) << 4);
    }

    auto STAGE = [&](int bufi, int chunk) {
        const char* ps = phC + (size_t)chunk * 8192 + w * 2048 + l * 16;
        const char* gs = gC  + (size_t)chunk * 8192 + w * 2048 + l * 16;
        char* pd = (char*)&phiL[bufi][0] + w * 2048;
        char* gd = (char*)&gL[bufi][0]  + w * 2048;
        gl16(ps, pd);           gl16(ps + 1024, pd + 1024);
        gl16(gs, gd);           gl16(gs + 1024, gd + 1024);
    };

    STAGE(0, 0);

    // theta A-frags (overlap with staging)
    bf16x8 afr[2][4];
#pragma unroll
    for (int nt = 0; nt < 2; ++nt)
#pragma unroll
        for (int kt = 0; kt < 4; ++kt)
            afr[nt][kt] = *(const bf16x8*)(thb + (size_t)(nt * 16 + lr) * CMID + kt * 32 + lg * 8);

    f32x4 o[2][8];
    float rm[2][4], ps_[2][4];
#pragma unroll
    for (int nt = 0; nt < 2; ++nt) {
#pragma unroll
        for (int dt = 0; dt < 8; ++dt)
#pragma unroll
            for (int e = 0; e < 4; ++e) o[nt][dt][e] = 0.f;
#pragma unroll
        for (int r = 0; r < 4; ++r) { rm[nt][r] = -1e30f; ps_[nt][r] = 0.f; }
    }

    asm volatile("s_waitcnt vmcnt(0)" ::: "memory");
    __syncthreads();

    for (int tc_ = 0; tc_ < 32; ++tc_) {
        const int cur = tc_ & 1;
        if (tc_ < 31) STAGE(cur ^ 1, tc_ + 1);

        const char* pb = (const char*)&phiL[cur][0];
        const char* gb = (const char*)&gL[cur][0];

        // ---- QK^T
        f32x4 s[2][2];
#pragma unroll
        for (int nt = 0; nt < 2; ++nt)
#pragma unroll
            for (int mt = 0; mt < 2; ++mt)
#pragma unroll
                for (int e = 0; e < 4; ++e) s[nt][mt][e] = 0.f;
#pragma unroll
        for (int kt = 0; kt < 4; ++kt) {
            bf16x8 b0 = *(const bf16x8*)(pb + phOff[kt][0]);
            bf16x8 b1 = *(const bf16x8*)(pb + phOff[kt][1]);
#pragma unroll
            for (int nt = 0; nt < 2; ++nt) {
                s[nt][0] = __builtin_amdgcn_mfma_f32_16x16x32_bf16(afr[nt][kt], b0, s[nt][0], 0, 0, 0);
                s[nt][1] = __builtin_amdgcn_mfma_f32_16x16x32_bf16(afr[nt][kt], b1, s[nt][1], 0, 0, 0);
            }
        }

        // ---- G fragments (LDS)
        bf16x8 gf[8];
#pragma unroll
        for (int dt = 0; dt < 8; ++dt)
            gf[dt] = *(const bf16x8*)(gb + gOff[dt]);

        // ---- defer-max online softmax
        int big = 0;
#pragma unroll
        for (int nt = 0; nt < 2; ++nt)
#pragma unroll
            for (int mt = 0; mt < 2; ++mt)
#pragma unroll
                for (int r = 0; r < 4; ++r)
                    big |= (s[nt][mt][r] > rm[nt][r] + 8.f) ? 1 : 0;
        if (__any(big)) {
#pragma unroll
            for (int nt = 0; nt < 2; ++nt)
#pragma unroll
                for (int r = 0; r < 4; ++r) {
                    float cm = fmaxf(s[nt][0][r], s[nt][1][r]);
#pragma unroll
                    for (int off = 8; off >= 1; off >>= 1)
                        cm = fmaxf(cm, __shfl_xor(cm, off));
                    float nm = fmaxf(rm[nt][r], cm);
                    float sc = __expf(rm[nt][r] - nm);
                    ps_[nt][r] *= sc;
                    rm[nt][r] = nm;
#pragma unroll
                    for (int dt = 0; dt < 8; ++dt) o[nt][dt][r] *= sc;
                }
        }

        // ---- P = exp(S - rm) -> bf16 LDS slab
#pragma unroll
        for (int nt = 0; nt < 2; ++nt)
#pragma unroll
            for (int mt = 0; mt < 2; ++mt)
#pragma unroll
                for (int r = 0; r < 4; ++r) {
                    float p = __expf(s[nt][mt][r] - rm[nt][r]);
                    ps_[nt][r] += p;
                    pl[(nt * 16 + lg * 4 + r) * 40 + mt * 16 + lr] = f2bf(p);
                }

        // ---- PV
#pragma unroll
        for (int nt = 0; nt < 2; ++nt) {
            bf16x8 pa = *(const bf16x8*)(pl + (size_t)(nt * 16 + lr) * 40 + lg * 8);
#pragma unroll
            for (int dt = 0; dt < 8; ++dt)
                o[nt][dt] = __builtin_amdgcn_mfma_f32_16x16x32_bf16(pa, gf[dt], o[nt][dt], 0, 0, 0);
        }

        asm volatile("s_waitcnt vmcnt(0)" ::: "memory");
        __syncthreads();
    }

    // ---- finalize
#pragma unroll
    for (int nt = 0; nt < 2; ++nt)
#pragma unroll
        for (int r = 0; r < 4; ++r) {
            float sTot = ps_[nt][r];
#pragma unroll
            for (int off = 8; off >= 1; off >>= 1) sTot += __shfl_xor(sTot, off);
            float inv = 1.f / sTot;
#pragma unroll
            for (int dt = 0; dt < 8; ++dt) {
                m2[((size_t)b * NPIX + n0 + nt * 16 + lg * 4 + r) * CMID + dt * 16 + lr]
                    = o[nt][dt][r] * inv;
            }
        }
}

extern "C" void kernel_launch(void* const* d_in, const int* in_sizes, int n_in,
                              void* d_out, int out_size, void* d_ws, size_t ws_size,
                              hipStream_t stream)
{
    const float* x       = (const float*)d_in[0];
    const float* theta_w = (const float*)d_in[1];
    const float* theta_b = (const float*)d_in[2];
    const float* phi_w   = (const float*)d_in[3];
    const float* phi_b   = (const float*)d_in[4];
    const float* g_w     = (const float*)d_in[5];
    const float* g_b     = (const float*)d_in[6];
    const float* wz_w    = (const float*)d_in[7];
    const float* wz_b    = (const float*)d_in[8];
    float* out = (float*)d_out;

    float* ws      = (float*)d_ws;
    float* xp      = ws;                               // [B,256,1024] f32
    float* m2      = xp + (size_t)2097152;             // [B,4096,128] f32
    short* theta_h = (short*)(m2 + (size_t)4194304);   // [B,4096,128] bf16
    short* phi_h   = theta_h + (size_t)4194304;        // [B,32,4096] bf16 swizzled
    short* G_h     = phi_h + (size_t)1048576;          // [B,32,4096] bf16 permuted

    maxpool_k<<<dim3(BATCH * CINCH * MPIX / 256), 256, 0, stream>>>(x, xp);

    conv1x1_k<CINCH, 1><<<dim3(NPIX / 32, 1, BATCH), 256, 0, stream>>>(
        x, theta_w, theta_b, nullptr, theta_h, NPIX, CMID);

    conv1x1_k<CINCH, 2><<<dim3(MPIX / 32, 1, BATCH), 256, 0, stream>>>(
        xp, phi_w, phi_b, nullptr, phi_h, MPIX, CMID);
    conv1x1_k<CINCH, 3><<<dim3(MPIX / 32, 1, BATCH), 256, 0, stream>>>(
        xp, g_w, g_b, nullptr, G_h, MPIX, CMID);

    attn_v3<<<dim3(256), 256, 0, stream>>>(theta_h, phi_h, G_h, m2);

    conv1x1_k<CMID, 0><<<dim3(NPIX / 32, CINCH / 128, BATCH), 256, 0, stream>>>(
        m2, wz_w, wz_b, x, out, NPIX, CINCH);
}

// Round 4
// 154.231 us; speedup vs baseline: 3.8495x; 1.2145x over previous
//
#include <hip/hip_runtime.h>
#include <math.h>

#define BATCH 8
#define CINCH 256
#define CMID  128
#define NPIX  4096   // 64*64
#define MPIX  1024   // 32*32

typedef __attribute__((ext_vector_type(8))) short bf16x8;
typedef __attribute__((ext_vector_type(4))) short s16x4;
typedef __attribute__((ext_vector_type(4))) float f32x4;

static __device__ __forceinline__ short f2bf(float f) {
    unsigned u = __float_as_uint(f);
    u = (u + 0x7fffu + ((u >> 16) & 1u)) >> 16;   // RNE bf16
    return (short)u;
}

static __device__ __forceinline__ bf16x8 cvt8(const float* p) {
    float4 f0 = *(const float4*)p;
    float4 f1 = *(const float4*)(p + 4);
    bf16x8 r = { f2bf(f0.x), f2bf(f0.y), f2bf(f0.z), f2bf(f0.w),
                 f2bf(f1.x), f2bf(f1.y), f2bf(f1.z), f2bf(f1.w) };
    return r;
}

static __device__ __forceinline__ void gl16(const void* g, void* l) {
    __builtin_amdgcn_global_load_lds(
        (const __attribute__((address_space(1))) void*)g,
        (__attribute__((address_space(3))) void*)l, 16, 0, 0);
}

// ---------------------------------------------------------------------------
// Fused transpose-cast + maxpool:
//   x[B,256,4096] f32 -> xT[B,4096,256] bf16, xpT[B,1024,256] bf16
// Block: (h-pair r, ch-tile 64, b); LDS tile [128 l][65 ch] f32.
// ---------------------------------------------------------------------------
__global__ __launch_bounds__(256)
void pool_transpose_k(const float* __restrict__ x, short* __restrict__ xT,
                      short* __restrict__ xpT)
{
    __shared__ float lds[128 * 65];
    const int r   = blockIdx.x;       // pooled row hp (0..31), covers l = r*128..+127
    const int cht = blockIdx.y;       // ch tile (0..3)
    const int b   = blockIdx.z;
    const int t   = threadIdx.x;
    const int wl  = t & 63;           // lane along w / ch
    const int cq  = t >> 6;           // 0..3

    const float* xb = x + ((size_t)b * 256 + cht * 64) * 4096 + r * 128;
#pragma unroll
    for (int hh = 0; hh < 2; ++hh)
#pragma unroll
        for (int i = 0; i < 16; ++i) {
            int ch = cq + i * 4;
            lds[(hh * 64 + wl) * 65 + ch] = xb[(size_t)ch * 4096 + hh * 64 + wl];
        }
    __syncthreads();

    // xT write: 128 l rows, 64 ch each
    short* xTb = xT + ((size_t)b * 4096 + r * 128) * 256 + cht * 64;
#pragma unroll
    for (int j = 0; j < 32; ++j) {
        int lrow = cq * 32 + j;
        xTb[(size_t)lrow * 256 + wl] = f2bf(lds[lrow * 65 + wl]);
    }
    // pooled write: 32 wp rows, 64 ch each
    short* xpb = xpT + ((size_t)b * 1024 + r * 32) * 256 + cht * 64;
#pragma unroll
    for (int k = 0; k < 8; ++k) {
        int wp = cq * 8 + k;
        float v = fmaxf(fmaxf(lds[(2 * wp) * 65 + wl], lds[(2 * wp + 1) * 65 + wl]),
                        fmaxf(lds[(64 + 2 * wp) * 65 + wl], lds[(64 + 2 * wp + 1) * 65 + wl]));
        xpb[(size_t)wp * 256 + wl] = f2bf(v);
    }
}

// ---------------------------------------------------------------------------
// MFMA conv1x1: out = inT[b][L][K=256] @ w[128 cout][256]^T + bias.
// 4 waves x (32 rows x 128 cout). A-frags direct from global inT (bf16),
// B-frags direct from global w (f32 -> cvt, L2-hot).
// EPI 0: theta -> [b][n][128] linear bf16
// EPI 1: phi   -> frag-order chunks [b][32][4096]
// EPI 2: g     -> frag-order chunks (G layout), packed rowmap
// ---------------------------------------------------------------------------
template<int EPI>
__global__ __launch_bounds__(256)
void mfma_conv_k(const short* __restrict__ inT, const float* __restrict__ w,
                 const float* __restrict__ bias, short* __restrict__ outp, int L)
{
    const int t  = threadIdx.x;
    const int wv = t >> 6;
    const int l  = t & 63;
    const int lr = l & 15;
    const int lg = l >> 4;
    const int b  = blockIdx.y;
    const int m0 = blockIdx.x * 128 + wv * 32;

    // abstract-row -> m mapping (i = row index 0..15 within nt-tile)
    // EPI 2 (G): m = m0 + (i>>2)*8 + nt*4 + (i&3)  -> lane's 8 accs are m-consecutive
    // else:      m = m0 + nt*16 + i
    int mA[2];
#pragma unroll
    for (int nt = 0; nt < 2; ++nt)
        mA[nt] = (EPI == 2) ? (m0 + (lr >> 2) * 8 + nt * 4 + (lr & 3))
                            : (m0 + nt * 16 + lr);

    const size_t inb = ((size_t)b * L) * 256 + lg * 8;
    const float* wp_[8];
#pragma unroll
    for (int dt = 0; dt < 8; ++dt)
        wp_[dt] = w + (size_t)(dt * 16 + lr) * 256 + lg * 8;

    f32x4 o[2][8];
#pragma unroll
    for (int nt = 0; nt < 2; ++nt)
#pragma unroll
        for (int dt = 0; dt < 8; ++dt)
#pragma unroll
            for (int e = 0; e < 4; ++e) o[nt][dt][e] = 0.f;

    for (int kt = 0; kt < 8; ++kt) {
        bf16x8 a0 = *(const bf16x8*)(inT + inb + (size_t)mA[0] * 256 + kt * 32);
        bf16x8 a1 = *(const bf16x8*)(inT + inb + (size_t)mA[1] * 256 + kt * 32);
#pragma unroll
        for (int dt = 0; dt < 8; ++dt) {
            bf16x8 bv = cvt8(wp_[dt] + kt * 32);
            o[0][dt] = __builtin_amdgcn_mfma_f32_16x16x32_bf16(a0, bv, o[0][dt], 0, 0, 0);
            o[1][dt] = __builtin_amdgcn_mfma_f32_16x16x32_bf16(a1, bv, o[1][dt], 0, 0, 0);
        }
    }

    float bv8[8];
#pragma unroll
    for (int dt = 0; dt < 8; ++dt) bv8[dt] = bias[dt * 16 + lr];

    if (EPI == 0) {          // theta [b][n][128]
        short* ob = outp + ((size_t)b * NPIX) * 128;
#pragma unroll
        for (int nt = 0; nt < 2; ++nt)
#pragma unroll
            for (int rr = 0; rr < 4; ++rr) {
                int n = m0 + nt * 16 + lg * 4 + rr;
#pragma unroll
                for (int dt = 0; dt < 8; ++dt)
                    ob[(size_t)n * 128 + dt * 16 + lr] = f2bf(o[nt][dt][rr] + bv8[dt]);
            }
    } else if (EPI == 1) {   // phi frag-order: granule ((cc>>5)*2+mt)*64+lg'*16+(m&15), j=cc&7
        short* ob = outp + (size_t)b * 32 * 4096;
#pragma unroll
        for (int nt = 0; nt < 2; ++nt)
#pragma unroll
            for (int rr = 0; rr < 4; ++rr) {
                int m = m0 + nt * 16 + lg * 4 + rr;
                short* cb = ob + (size_t)(m >> 5) * 4096 + ((m >> 4) & 1) * 512 + (m & 15) * 8;
#pragma unroll
                for (int dt = 0; dt < 8; ++dt) {
                    int cc = dt * 16 + lr;
                    cb[(cc >> 5) * 1024 + ((cc >> 3) & 3) * 128 + (cc & 7)]
                        = f2bf(o[nt][dt][rr] + bv8[dt]);
                }
            }
    } else {                 // G frag-order: granule dt*64+lg*16+lr, j = m&7 (packed)
        short* ob = outp + (size_t)b * 32 * 4096 + (size_t)(m0 >> 5) * 4096;
#pragma unroll
        for (int dt = 0; dt < 8; ++dt) {
            bf16x8 sv;
#pragma unroll
            for (int j = 0; j < 8; ++j)
                sv[j] = f2bf(o[j >> 2][dt][j & 3] + bv8[dt]);
            *(bf16x8*)(ob + (size_t)(dt * 64 + lg * 16 + lr) * 8) = sv;
        }
    }
}

// ---------------------------------------------------------------------------
// MFMA attention. theta [B,N,128] bf16; phi_sw/G_sw frag-order chunks.
// Rowmap: abstract row i (nt) -> n = nbase + (i>>2) + 32*(nt*4 + (i&3)), so a
// lane's 8 accs (nt,r) are 8 consecutive cm = n>>5 -> packed Z-writes.
// Z[b][seg 16][l 4096][8 cm] bf16 = final-conv B-frag order.
// ---------------------------------------------------------------------------
__global__ __launch_bounds__(256)
void attn_v4(const short* __restrict__ theta, const short* __restrict__ phi_sw,
             const short* __restrict__ G_sw, short* __restrict__ Z)
{
    __shared__ short phiL[2][4096];   // frag-order chunk (8KB)
    __shared__ short gL[2][4096];
    __shared__ short pl4[4][1024];    // per-wave P slab, frag-order (2KB)

    const int t  = threadIdx.x;
    const int wv = t >> 6;
    const int l  = t & 63;
    const int lr = l & 15;
    const int lg = l >> 4;
    const int bid  = blockIdx.x;
    const int b    = bid & 7;          // batch -> XCD
    const int rest = bid >> 3;         // 0..31
    const int seg  = rest >> 1;        // n>>8 (0..15)
    const int Nblk = (rest & 1) * 16;
    const int nbase = seg * 256 + Nblk + wv * 4;

    const short* thb = theta + (size_t)b * NPIX * 128;
    const char*  phC = (const char*)phi_sw + (size_t)b * 32 * 8192;
    const char*  gC  = (const char*)G_sw  + (size_t)b * 32 * 8192;
    short* pl = &pl4[wv][0];

    auto STAGE = [&](int bufi, int chunk) {
        const char* ps = phC + (size_t)chunk * 8192 + wv * 2048 + l * 16;
        const char* gs = gC  + (size_t)chunk * 8192 + wv * 2048 + l * 16;
        char* pd = (char*)&phiL[bufi][0] + wv * 2048;
        char* gd = (char*)&gL[bufi][0]  + wv * 2048;
        gl16(ps, pd);           gl16(ps + 1024, pd + 1024);
        gl16(gs, gd);           gl16(gs + 1024, gd + 1024);
    };

    STAGE(0, 0);

    // theta A-frags, rowmap rows
    bf16x8 afr[2][4];
#pragma unroll
    for (int nt = 0; nt < 2; ++nt) {
        int n = nbase + (lr >> 2) + 32 * (nt * 4 + (lr & 3));
#pragma unroll
        for (int kt = 0; kt < 4; ++kt)
            afr[nt][kt] = *(const bf16x8*)(thb + (size_t)n * 128 + kt * 32 + lg * 8);
    }

    f32x4 o[2][8];
    float rm[2][4], ps_[2][4];
#pragma unroll
    for (int nt = 0; nt < 2; ++nt) {
#pragma unroll
        for (int dt = 0; dt < 8; ++dt)
#pragma unroll
            for (int e = 0; e < 4; ++e) o[nt][dt][e] = 0.f;
#pragma unroll
        for (int rr = 0; rr < 4; ++rr) { rm[nt][rr] = -1e30f; ps_[nt][rr] = 0.f; }
    }

    asm volatile("s_waitcnt vmcnt(0)" ::: "memory");
    __syncthreads();

    for (int tc_ = 0; tc_ < 32; ++tc_) {
        const int cur = tc_ & 1;
        if (tc_ < 31) STAGE(cur ^ 1, tc_ + 1);

        const char* pb = (const char*)&phiL[cur][0];
        const char* gb = (const char*)&gL[cur][0];

        // ---- QK^T: B-frags linear frag-order (consecutive lanes -> consecutive 16B)
        f32x4 s[2][2];
#pragma unroll
        for (int nt = 0; nt < 2; ++nt)
#pragma unroll
            for (int mt = 0; mt < 2; ++mt)
#pragma unroll
                for (int e = 0; e < 4; ++e) s[nt][mt][e] = 0.f;
#pragma unroll
        for (int kt = 0; kt < 4; ++kt) {
            bf16x8 b0 = *(const bf16x8*)(pb + ((kt * 2 + 0) * 64 + l) * 16);
            bf16x8 b1 = *(const bf16x8*)(pb + ((kt * 2 + 1) * 64 + l) * 16);
#pragma unroll
            for (int nt = 0; nt < 2; ++nt) {
                s[nt][0] = __builtin_amdgcn_mfma_f32_16x16x32_bf16(afr[nt][kt], b0, s[nt][0], 0, 0, 0);
                s[nt][1] = __builtin_amdgcn_mfma_f32_16x16x32_bf16(afr[nt][kt], b1, s[nt][1], 0, 0, 0);
            }
        }

        // ---- G fragments (frag-order linear)
        bf16x8 gf[8];
#pragma unroll
        for (int dt = 0; dt < 8; ++dt)
            gf[dt] = *(const bf16x8*)(gb + (dt * 64 + l) * 16);

        // ---- defer-max online softmax
        int big = 0;
#pragma unroll
        for (int nt = 0; nt < 2; ++nt)
#pragma unroll
            for (int mt = 0; mt < 2; ++mt)
#pragma unroll
                for (int rr = 0; rr < 4; ++rr)
                    big |= (s[nt][mt][rr] > rm[nt][rr] + 8.f) ? 1 : 0;
        if (__any(big)) {
#pragma unroll
            for (int nt = 0; nt < 2; ++nt)
#pragma unroll
                for (int rr = 0; rr < 4; ++rr) {
                    float cm = fmaxf(s[nt][0][rr], s[nt][1][rr]);
#pragma unroll
                    for (int off = 8; off >= 1; off >>= 1)
                        cm = fmaxf(cm, __shfl_xor(cm, off));
                    float nm = fmaxf(rm[nt][rr], cm);
                    float sc = __expf(rm[nt][rr] - nm);
                    ps_[nt][rr] *= sc;
                    rm[nt][rr] = nm;
#pragma unroll
                    for (int dt = 0; dt < 8; ++dt) o[nt][dt][rr] *= sc;
                }
        }

        // ---- P = exp(S-rm) -> frag-order slab: granule nt*64+(key>>3)*16+i, j=key&7
#pragma unroll
        for (int nt = 0; nt < 2; ++nt)
#pragma unroll
            for (int mt = 0; mt < 2; ++mt)
#pragma unroll
                for (int rr = 0; rr < 4; ++rr) {
                    float p = __expf(s[nt][mt][rr] - rm[nt][rr]);
                    ps_[nt][rr] += p;
                    pl[((nt * 64 + (mt * 2 + (lr >> 3)) * 16 + lg * 4 + rr) << 3) + (lr & 7)]
                        = f2bf(p);
                }

        // ---- PV: P A-frags linear; G B-frags in regs
#pragma unroll
        for (int nt = 0; nt < 2; ++nt) {
            bf16x8 pa = *(const bf16x8*)(pl + nt * 512 + l * 8);
#pragma unroll
            for (int dt = 0; dt < 8; ++dt)
                o[nt][dt] = __builtin_amdgcn_mfma_f32_16x16x32_bf16(pa, gf[dt], o[nt][dt], 0, 0, 0);
        }

        asm volatile("s_waitcnt vmcnt(0)" ::: "memory");
        __syncthreads();
    }

    // ---- finalize: per-row inv, packed Z writes (16B, coalesced)
    float inv[2][4];
#pragma unroll
    for (int nt = 0; nt < 2; ++nt)
#pragma unroll
        for (int rr = 0; rr < 4; ++rr) {
            float sTot = ps_[nt][rr];
#pragma unroll
            for (int off = 8; off >= 1; off >>= 1) sTot += __shfl_xor(sTot, off);
            inv[nt][rr] = 1.f / sTot;
        }
    short* Zb = Z + ((size_t)b * 16 + seg) * 4096 * 8;
    const int lq0 = (Nblk + wv * 4 + lg) * 128;
#pragma unroll
    for (int dt = 0; dt < 8; ++dt) {
        bf16x8 sv;
#pragma unroll
        for (int j = 0; j < 8; ++j)
            sv[j] = f2bf(o[j >> 2][dt][j & 3] * inv[j >> 2][j & 3]);
        *(bf16x8*)(Zb + (size_t)(lq0 + dt * 16 + lr) * 8) = sv;
    }
}

// ---------------------------------------------------------------------------
// Final conv: out[b][256 co][4096 l] = wz[256,128] @ m3 + bias + x.
// A = wz (direct global f32->bf16); B = Z frag-order (direct global bf16).
// Block: 4 waves = 2 co x 2 l; wave = 32 co x 128 l.
// ---------------------------------------------------------------------------
__global__ __launch_bounds__(256)
void conv_fin_k(const short* __restrict__ Z, const float* __restrict__ wz,
                const float* __restrict__ wzb, const float* __restrict__ x,
                float* __restrict__ out)
{
    const int t  = threadIdx.x;
    const int wv = t >> 6;
    const int l  = t & 63;
    const int lr = l & 15;
    const int lg = l >> 4;
    const int b  = blockIdx.z;
    const int co0 = blockIdx.y * 64 + (wv >> 1) * 32;
    const int l0  = blockIdx.x * 256 + (wv & 1) * 128;

    bf16x8 afr[2][4];
#pragma unroll
    for (int nt = 0; nt < 2; ++nt) {
        int co = co0 + nt * 16 + lr;
#pragma unroll
        for (int kt = 0; kt < 4; ++kt)
            afr[nt][kt] = cvt8(wz + (size_t)co * 128 + kt * 32 + lg * 8);
    }

    const short* Zb = Z + (size_t)b * 16 * 4096 * 8;
    f32x4 o[2][8];
#pragma unroll
    for (int nt = 0; nt < 2; ++nt)
#pragma unroll
        for (int dt = 0; dt < 8; ++dt)
#pragma unroll
            for (int e = 0; e < 4; ++e) o[nt][dt][e] = 0.f;

#pragma unroll
    for (int dt = 0; dt < 8; ++dt) {
        int lpix = l0 + dt * 16 + lr;
#pragma unroll
        for (int kt = 0; kt < 4; ++kt) {
            bf16x8 bz = *(const bf16x8*)(Zb + ((size_t)(kt * 4 + lg) * 4096 + lpix) * 8);
            o[0][dt] = __builtin_amdgcn_mfma_f32_16x16x32_bf16(afr[0][kt], bz, o[0][dt], 0, 0, 0);
            o[1][dt] = __builtin_amdgcn_mfma_f32_16x16x32_bf16(afr[1][kt], bz, o[1][dt], 0, 0, 0);
        }
    }

#pragma unroll
    for (int nt = 0; nt < 2; ++nt)
#pragma unroll
        for (int rr = 0; rr < 4; ++rr) {
            int co = co0 + nt * 16 + lg * 4 + rr;
            float bv = wzb[co];
            const float* xb = x + ((size_t)b * 256 + co) * 4096;
            float* ob = out + ((size_t)b * 256 + co) * 4096;
#pragma unroll
            for (int dt = 0; dt < 8; ++dt) {
                int lpix = l0 + dt * 16 + lr;
                ob[lpix] = o[nt][dt][rr] + bv + xb[lpix];
            }
        }
}

extern "C" void kernel_launch(void* const* d_in, const int* in_sizes, int n_in,
                              void* d_out, int out_size, void* d_ws, size_t ws_size,
                              hipStream_t stream)
{
    const float* x       = (const float*)d_in[0];
    const float* theta_w = (const float*)d_in[1];
    const float* theta_b = (const float*)d_in[2];
    const float* phi_w   = (const float*)d_in[3];
    const float* phi_b   = (const float*)d_in[4];
    const float* g_w     = (const float*)d_in[5];
    const float* g_b     = (const float*)d_in[6];
    const float* wz_w    = (const float*)d_in[7];
    const float* wz_b    = (const float*)d_in[8];
    float* out = (float*)d_out;

    short* ws      = (short*)d_ws;
    short* xT      = ws;                         // [B,4096,256]  8388608 shorts
    short* xpT     = xT  + (size_t)8388608;      // [B,1024,256]  2097152
    short* theta_h = xpT + (size_t)2097152;      // [B,4096,128]  4194304
    short* phi_h   = theta_h + (size_t)4194304;  // [B,32,4096]   1048576 (frag-order)
    short* G_h     = phi_h + (size_t)1048576;    // [B,32,4096]   1048576 (frag-order)
    short* Z       = G_h  + (size_t)1048576;     // [B,16,4096,8] 4194304 (B-frag order)

    pool_transpose_k<<<dim3(32, 4, BATCH), 256, 0, stream>>>(x, xT, xpT);

    mfma_conv_k<0><<<dim3(NPIX / 128, BATCH), 256, 0, stream>>>(
        xT, theta_w, theta_b, theta_h, NPIX);
    mfma_conv_k<1><<<dim3(MPIX / 128, BATCH), 256, 0, stream>>>(
        xpT, phi_w, phi_b, phi_h, MPIX);
    mfma_conv_k<2><<<dim3(MPIX / 128, BATCH), 256, 0, stream>>>(
        xpT, g_w, g_b, G_h, MPIX);

    attn_v4<<<dim3(256), 256, 0, stream>>>(theta_h, phi_h, G_h, Z);

    conv_fin_k<<<dim3(16, 4, BATCH), 256, 0, stream>>>(Z, wz_w, wz_b, x, out);
}

// Round 5
// 114.118 us; speedup vs baseline: 5.2026x; 1.3515x over previous
//
#include <hip/hip_runtime.h>
#include <math.h>

#define BATCH 8
#define CINCH 256
#define CMID  128
#define NPIX  4096   // 64*64
#define MPIX  1024   // 32*32

typedef __attribute__((ext_vector_type(8))) short bf16x8;
typedef __attribute__((ext_vector_type(4))) short s16x4;
typedef __attribute__((ext_vector_type(4))) float f32x4;

static __device__ __forceinline__ short f2bf(float f) {
    unsigned u = __float_as_uint(f);
    u = (u + 0x7fffu + ((u >> 16) & 1u)) >> 16;   // RNE bf16
    return (short)u;
}

static __device__ __forceinline__ void gl16(const void* g, void* l) {
    __builtin_amdgcn_global_load_lds(
        (const __attribute__((address_space(1))) void*)g,
        (__attribute__((address_space(3))) void*)l, 16, 0, 0);
}

// ---------------------------------------------------------------------------
// Weight f32->bf16 pre-convert (theta_w, phi_w, g_w, wz_w -> one bf16 buffer)
// ---------------------------------------------------------------------------
__global__ __launch_bounds__(256)
void wcvt_k(const float* __restrict__ a, const float* __restrict__ b,
            const float* __restrict__ c, const float* __restrict__ d,
            short* __restrict__ o)
{
    int i = (blockIdx.x * 256 + threadIdx.x) * 4;   // 131072 total
    const float* src; int j;
    if (i < 32768)       { src = a; j = i; }
    else if (i < 65536)  { src = b; j = i - 32768; }
    else if (i < 98304)  { src = c; j = i - 65536; }
    else                 { src = d; j = i - 98304; }
    float4 v = *(const float4*)(src + j);
    s16x4 r = { f2bf(v.x), f2bf(v.y), f2bf(v.z), f2bf(v.w) };
    *(s16x4*)(o + i) = r;
}

// ---------------------------------------------------------------------------
// Fused transpose-cast + maxpool:
//   x[B,256,4096] f32 -> xT[B,4096,256] bf16, xpT[B,1024,256] bf16
// ---------------------------------------------------------------------------
__global__ __launch_bounds__(256)
void pool_transpose_k(const float* __restrict__ x, short* __restrict__ xT,
                      short* __restrict__ xpT)
{
    __shared__ float lds[128 * 65];
    const int r   = blockIdx.x;       // pooled row hp (0..31)
    const int cht = blockIdx.y;       // ch tile (0..3)
    const int b   = blockIdx.z;
    const int t   = threadIdx.x;
    const int wl  = t & 63;
    const int cq  = t >> 6;

    const float* xb = x + ((size_t)b * 256 + cht * 64) * 4096 + r * 128;
#pragma unroll
    for (int hh = 0; hh < 2; ++hh)
#pragma unroll
        for (int i = 0; i < 16; ++i) {
            int ch = cq + i * 4;
            lds[(hh * 64 + wl) * 65 + ch] = xb[(size_t)ch * 4096 + hh * 64 + wl];
        }
    __syncthreads();

    short* xTb = xT + ((size_t)b * 4096 + r * 128) * 256 + cht * 64;
#pragma unroll
    for (int j = 0; j < 32; ++j) {
        int lrow = cq * 32 + j;
        xTb[(size_t)lrow * 256 + wl] = f2bf(lds[lrow * 65 + wl]);
    }
    short* xpb = xpT + ((size_t)b * 1024 + r * 32) * 256 + cht * 64;
#pragma unroll
    for (int k = 0; k < 8; ++k) {
        int wp = cq * 8 + k;
        float v = fmaxf(fmaxf(lds[(2 * wp) * 65 + wl], lds[(2 * wp + 1) * 65 + wl]),
                        fmaxf(lds[(64 + 2 * wp) * 65 + wl], lds[(64 + 2 * wp + 1) * 65 + wl]));
        xpb[(size_t)wp * 256 + wl] = f2bf(v);
    }
}

// ---------------------------------------------------------------------------
// MFMA conv1x1 (theta): bf16 weights direct. out [b][n][128] linear bf16.
// ---------------------------------------------------------------------------
__global__ __launch_bounds__(256)
void mfma_conv_th_k(const short* __restrict__ inT, const short* __restrict__ wh,
                    const float* __restrict__ bias, short* __restrict__ outp, int L)
{
    const int t  = threadIdx.x;
    const int wv = t >> 6;
    const int l  = t & 63;
    const int lr = l & 15;
    const int lg = l >> 4;
    const int b  = blockIdx.y;
    const int m0 = blockIdx.x * 128 + wv * 32;

    const size_t inb = ((size_t)b * L) * 256 + lg * 8;

    f32x4 o[2][8];
#pragma unroll
    for (int nt = 0; nt < 2; ++nt)
#pragma unroll
        for (int dt = 0; dt < 8; ++dt)
#pragma unroll
            for (int e = 0; e < 4; ++e) o[nt][dt][e] = 0.f;

    for (int kt = 0; kt < 8; ++kt) {
        bf16x8 a0 = *(const bf16x8*)(inT + inb + (size_t)(m0 + lr) * 256 + kt * 32);
        bf16x8 a1 = *(const bf16x8*)(inT + inb + (size_t)(m0 + 16 + lr) * 256 + kt * 32);
#pragma unroll
        for (int dt = 0; dt < 8; ++dt) {
            bf16x8 bv = *(const bf16x8*)(wh + (size_t)(dt * 16 + lr) * 256 + kt * 32 + lg * 8);
            o[0][dt] = __builtin_amdgcn_mfma_f32_16x16x32_bf16(a0, bv, o[0][dt], 0, 0, 0);
            o[1][dt] = __builtin_amdgcn_mfma_f32_16x16x32_bf16(a1, bv, o[1][dt], 0, 0, 0);
        }
    }

    float bv8[8];
#pragma unroll
    for (int dt = 0; dt < 8; ++dt) bv8[dt] = bias[dt * 16 + lr];

    short* ob = outp + ((size_t)b * NPIX) * 128;
#pragma unroll
    for (int nt = 0; nt < 2; ++nt)
#pragma unroll
        for (int rr = 0; rr < 4; ++rr) {
            int n = m0 + nt * 16 + lg * 4 + rr;
#pragma unroll
            for (int dt = 0; dt < 8; ++dt)
                ob[(size_t)n * 128 + dt * 16 + lr] = f2bf(o[nt][dt][rr] + bv8[dt]);
        }
}

// ---------------------------------------------------------------------------
// Fused phi+g conv (blockIdx.z: 0=phi EPI1, 1=g EPI2), bf16 weights direct.
// phi frag-order chunks [b][32][4096]; G frag-order chunks (ch-major).
// ---------------------------------------------------------------------------
__global__ __launch_bounds__(256)
void mfma_conv_pg_k(const short* __restrict__ inT,
                    const short* __restrict__ wph, const float* __restrict__ pbias,
                    const short* __restrict__ wgh, const float* __restrict__ gbias,
                    short* __restrict__ phiO, short* __restrict__ gO)
{
    const int t  = threadIdx.x;
    const int wv = t >> 6;
    const int l  = t & 63;
    const int lr = l & 15;
    const int lg = l >> 4;
    const int b  = blockIdx.y;
    const int ep = blockIdx.z;          // 0: phi, 1: g
    const int m0 = blockIdx.x * 128 + wv * 32;

    const short* wh = ep ? wgh : wph;
    const float* bias = ep ? gbias : pbias;

    int mA[2];
#pragma unroll
    for (int nt = 0; nt < 2; ++nt)
        mA[nt] = ep ? (m0 + (lr >> 2) * 8 + nt * 4 + (lr & 3))
                    : (m0 + nt * 16 + lr);

    const size_t inb = ((size_t)b * MPIX) * 256 + lg * 8;

    f32x4 o[2][8];
#pragma unroll
    for (int nt = 0; nt < 2; ++nt)
#pragma unroll
        for (int dt = 0; dt < 8; ++dt)
#pragma unroll
            for (int e = 0; e < 4; ++e) o[nt][dt][e] = 0.f;

    for (int kt = 0; kt < 8; ++kt) {
        bf16x8 a0 = *(const bf16x8*)(inT + inb + (size_t)mA[0] * 256 + kt * 32);
        bf16x8 a1 = *(const bf16x8*)(inT + inb + (size_t)mA[1] * 256 + kt * 32);
#pragma unroll
        for (int dt = 0; dt < 8; ++dt) {
            bf16x8 bv = *(const bf16x8*)(wh + (size_t)(dt * 16 + lr) * 256 + kt * 32 + lg * 8);
            o[0][dt] = __builtin_amdgcn_mfma_f32_16x16x32_bf16(a0, bv, o[0][dt], 0, 0, 0);
            o[1][dt] = __builtin_amdgcn_mfma_f32_16x16x32_bf16(a1, bv, o[1][dt], 0, 0, 0);
        }
    }

    float bv8[8];
#pragma unroll
    for (int dt = 0; dt < 8; ++dt) bv8[dt] = bias[dt * 16 + lr];

    if (ep == 0) {   // phi frag-order
        short* ob = phiO + (size_t)b * 32 * 4096;
#pragma unroll
        for (int nt = 0; nt < 2; ++nt)
#pragma unroll
            for (int rr = 0; rr < 4; ++rr) {
                int m = m0 + nt * 16 + lg * 4 + rr;
                short* cb = ob + (size_t)(m >> 5) * 4096 + ((m >> 4) & 1) * 512 + (m & 15) * 8;
#pragma unroll
                for (int dt = 0; dt < 8; ++dt) {
                    int cc = dt * 16 + lr;
                    cb[(cc >> 5) * 1024 + ((cc >> 3) & 3) * 128 + (cc & 7)]
                        = f2bf(o[nt][dt][rr] + bv8[dt]);
                }
            }
    } else {         // G frag-order (packed rowmap)
        short* ob = gO + (size_t)b * 32 * 4096 + (size_t)(m0 >> 5) * 4096;
#pragma unroll
        for (int dt = 0; dt < 8; ++dt) {
            bf16x8 sv;
#pragma unroll
            for (int j = 0; j < 8; ++j)
                sv[j] = f2bf(o[j >> 2][dt][j & 3] + bv8[dt]);
            *(bf16x8*)(ob + (size_t)(dt * 64 + lg * 16 + lr) * 8) = sv;
        }
    }
}

// ---------------------------------------------------------------------------
// MFMA attention v5: 512 threads = 8 waves x 16 q-rows (rows strided 32).
// Swapped QK^T: S^T = mfma(A=phi, B=theta) -> lane owns query col lr.
// P-store = 2x packed 8B (conflict-free); PV: O = mfma(A=P, B=G).
// Z[b][16 kblk][4096 l][8] bf16 = final-conv B-frag order.
// ---------------------------------------------------------------------------
__global__ __launch_bounds__(512)
void attn_v5(const short* __restrict__ theta, const short* __restrict__ phi_sw,
             const short* __restrict__ G_sw, short* __restrict__ Z)
{
    __shared__ short phiL[2][4096];
    __shared__ short gL[2][4096];
    __shared__ short pl8[8][512];

    const int t  = threadIdx.x;
    const int wv = t >> 6;
    const int l  = t & 63;
    const int lr = l & 15;
    const int lg = l >> 4;
    const int bid = blockIdx.x;
    const int b   = bid & 7;            // batch -> XCD
    const int s   = bid >> 3;           // 0..31: n & 31

    const short* thb = theta + (size_t)b * NPIX * 128;
    const char*  phC = (const char*)phi_sw + (size_t)b * 32 * 8192;
    const char*  gC  = (const char*)G_sw  + (size_t)b * 32 * 8192;
    short* pl = &pl8[wv][0];

    auto STAGE = [&](int bufi, int chunk) {
        const char* ps = phC + (size_t)chunk * 8192 + wv * 1024 + l * 16;
        const char* gs = gC  + (size_t)chunk * 8192 + wv * 1024 + l * 16;
        gl16(ps, (char*)&phiL[bufi][0] + wv * 1024);
        gl16(gs, (char*)&gL[bufi][0]  + wv * 1024);
    };

    STAGE(0, 0);

    // theta B-frags: query n(j) = (wv*16 + j)*32 + s; lane j=lr
    bf16x8 bq[4];
    {
        int n = (wv * 16 + lr) * 32 + s;
#pragma unroll
        for (int kt = 0; kt < 4; ++kt)
            bq[kt] = *(const bf16x8*)(thb + (size_t)n * 128 + kt * 32 + lg * 8);
    }

    f32x4 o[8];
#pragma unroll
    for (int dt = 0; dt < 8; ++dt)
#pragma unroll
        for (int e = 0; e < 4; ++e) o[dt][e] = 0.f;
    float rm = -1e30f, ps_ = 0.f;

    asm volatile("s_waitcnt vmcnt(0)" ::: "memory");
    __syncthreads();

    for (int tc_ = 0; tc_ < 32; ++tc_) {
        const int cur = tc_ & 1;
        if (tc_ < 31) STAGE(cur ^ 1, tc_ + 1);

        const char* pb = (const char*)&phiL[cur][0];
        const char* gb = (const char*)&gL[cur][0];

        // ---- S^T = mfma(A=phi rows m, B=theta rows n) -> D[key][query]
        f32x4 ssw[2];
#pragma unroll
        for (int mt = 0; mt < 2; ++mt)
#pragma unroll
            for (int e = 0; e < 4; ++e) ssw[mt][e] = 0.f;
#pragma unroll
        for (int kt = 0; kt < 4; ++kt) {
            bf16x8 a0 = *(const bf16x8*)(pb + ((kt * 2 + 0) * 64 + l) * 16);
            bf16x8 a1 = *(const bf16x8*)(pb + ((kt * 2 + 1) * 64 + l) * 16);
            ssw[0] = __builtin_amdgcn_mfma_f32_16x16x32_bf16(a0, bq[kt], ssw[0], 0, 0, 0);
            ssw[1] = __builtin_amdgcn_mfma_f32_16x16x32_bf16(a1, bq[kt], ssw[1], 0, 0, 0);
        }

        // ---- G B-frags (ch rows)
        bf16x8 gf[8];
#pragma unroll
        for (int dt = 0; dt < 8; ++dt)
            gf[dt] = *(const bf16x8*)(gb + (dt * 64 + l) * 16);

        // ---- defer-max online softmax (query col = lr)
        float cmx = fmaxf(fmaxf(fmaxf(ssw[0][0], ssw[0][1]), fmaxf(ssw[0][2], ssw[0][3])),
                          fmaxf(fmaxf(ssw[1][0], ssw[1][1]), fmaxf(ssw[1][2], ssw[1][3])));
        if (__any(cmx > rm + 8.f)) {
            float cm = cmx;
            cm = fmaxf(cm, __shfl_xor(cm, 16));
            cm = fmaxf(cm, __shfl_xor(cm, 32));
            float nm = fmaxf(rm, cm);
            float sc = __expf(rm - nm);
            ps_ *= sc;
            rm = nm;
            float scg[4];
#pragma unroll
            for (int rr = 0; rr < 4; ++rr) scg[rr] = __shfl(sc, lg * 4 + rr);
#pragma unroll
            for (int dt = 0; dt < 8; ++dt)
#pragma unroll
                for (int rr = 0; rr < 4; ++rr) o[dt][rr] *= scg[rr];
        }

        // ---- P = exp(S^T - rm): packed 8B stores, conflict-free
#pragma unroll
        for (int mt = 0; mt < 2; ++mt) {
            s16x4 pv;
#pragma unroll
            for (int rr = 0; rr < 4; ++rr) {
                float p = __expf(ssw[mt][rr] - rm);
                ps_ += p;
                pv[rr] = f2bf(p);
            }
            *(s16x4*)(pl + ((mt * 2 + (lg >> 1)) * 16 + lr) * 8 + (lg & 1) * 4) = pv;
        }

        // ---- PV: A = P (rows = queries), B = G
        bf16x8 pa = *(const bf16x8*)(pl + l * 8);
#pragma unroll
        for (int dt = 0; dt < 8; ++dt)
            o[dt] = __builtin_amdgcn_mfma_f32_16x16x32_bf16(pa, gf[dt], o[dt], 0, 0, 0);

        asm volatile("s_waitcnt vmcnt(0)" ::: "memory");
        __syncthreads();
    }

    // ---- finalize: inv per query, gathered to O rows; packed Z writes
    float tot = ps_;
    tot += __shfl_xor(tot, 16);
    tot += __shfl_xor(tot, 32);
    float inv = 1.f / tot;
    float invg[4];
#pragma unroll
    for (int rr = 0; rr < 4; ++rr) invg[rr] = __shfl(inv, lg * 4 + rr);

    short* Zb = Z + (size_t)b * 16 * 4096 * 8;
#pragma unroll
    for (int dt = 0; dt < 8; ++dt) {
        s16x4 zv;
#pragma unroll
        for (int rr = 0; rr < 4; ++rr) zv[rr] = f2bf(o[dt][rr] * invg[rr]);
        size_t g = (size_t)(wv * 2 + (lg >> 1)) * 4096 + s * 128 + dt * 16 + lr;
        *(s16x4*)(Zb + g * 8 + (lg & 1) * 4) = zv;
    }
}

// ---------------------------------------------------------------------------
// Final conv: out[b][256 co][4096 l] = wz @ m3 + bias + x. bf16 wz direct.
// ---------------------------------------------------------------------------
__global__ __launch_bounds__(256)
void conv_fin_k(const short* __restrict__ Z, const short* __restrict__ wzh,
                const float* __restrict__ wzb, const float* __restrict__ x,
                float* __restrict__ out)
{
    const int t  = threadIdx.x;
    const int wv = t >> 6;
    const int l  = t & 63;
    const int lr = l & 15;
    const int lg = l >> 4;
    const int b  = blockIdx.z;
    const int co0 = blockIdx.y * 64 + (wv >> 1) * 32;
    const int l0  = blockIdx.x * 256 + (wv & 1) * 128;

    bf16x8 afr[2][4];
#pragma unroll
    for (int nt = 0; nt < 2; ++nt) {
        int co = co0 + nt * 16 + lr;
#pragma unroll
        for (int kt = 0; kt < 4; ++kt)
            afr[nt][kt] = *(const bf16x8*)(wzh + (size_t)co * 128 + kt * 32 + lg * 8);
    }

    const short* Zb = Z + (size_t)b * 16 * 4096 * 8;
    f32x4 o[2][8];
#pragma unroll
    for (int nt = 0; nt < 2; ++nt)
#pragma unroll
        for (int dt = 0; dt < 8; ++dt)
#pragma unroll
            for (int e = 0; e < 4; ++e) o[nt][dt][e] = 0.f;

#pragma unroll
    for (int dt = 0; dt < 8; ++dt) {
        int lpix = l0 + dt * 16 + lr;
#pragma unroll
        for (int kt = 0; kt < 4; ++kt) {
            bf16x8 bz = *(const bf16x8*)(Zb + ((size_t)(kt * 4 + lg) * 4096 + lpix) * 8);
            o[0][dt] = __builtin_amdgcn_mfma_f32_16x16x32_bf16(afr[0][kt], bz, o[0][dt], 0, 0, 0);
            o[1][dt] = __builtin_amdgcn_mfma_f32_16x16x32_bf16(afr[1][kt], bz, o[1][dt], 0, 0, 0);
        }
    }

#pragma unroll
    for (int nt = 0; nt < 2; ++nt)
#pragma unroll
        for (int rr = 0; rr < 4; ++rr) {
            int co = co0 + nt * 16 + lg * 4 + rr;
            float bv = wzb[co];
            const float* xb = x + ((size_t)b * 256 + co) * 4096;
            float* ob = out + ((size_t)b * 256 + co) * 4096;
#pragma unroll
            for (int dt = 0; dt < 8; ++dt) {
                int lpix = l0 + dt * 16 + lr;
                ob[lpix] = o[nt][dt][rr] + bv + xb[lpix];
            }
        }
}

extern "C" void kernel_launch(void* const* d_in, const int* in_sizes, int n_in,
                              void* d_out, int out_size, void* d_ws, size_t ws_size,
                              hipStream_t stream)
{
    const float* x       = (const float*)d_in[0];
    const float* theta_w = (const float*)d_in[1];
    const float* theta_b = (const float*)d_in[2];
    const float* phi_w   = (const float*)d_in[3];
    const float* phi_b   = (const float*)d_in[4];
    const float* g_w     = (const float*)d_in[5];
    const float* g_b     = (const float*)d_in[6];
    const float* wz_w    = (const float*)d_in[7];
    const float* wz_b    = (const float*)d_in[8];
    float* out = (float*)d_out;

    short* ws      = (short*)d_ws;
    short* xT      = ws;                         // [B,4096,256]  8388608
    short* xpT     = xT  + (size_t)8388608;      // [B,1024,256]  2097152
    short* theta_h = xpT + (size_t)2097152;      // [B,4096,128]  4194304
    short* phi_h   = theta_h + (size_t)4194304;  // [B,32,4096]   1048576
    short* G_h     = phi_h + (size_t)1048576;    // [B,32,4096]   1048576
    short* Z       = G_h  + (size_t)1048576;     // [B,16,4096,8] 4194304
    short* wh      = Z    + (size_t)4194304;     // 131072 bf16 weights
    short* th_wh = wh;
    short* ph_wh = wh + 32768;
    short* g_wh  = wh + 65536;
    short* wz_wh = wh + 98304;

    wcvt_k<<<dim3(128), 256, 0, stream>>>(theta_w, phi_w, g_w, wz_w, wh);

    pool_transpose_k<<<dim3(32, 4, BATCH), 256, 0, stream>>>(x, xT, xpT);

    mfma_conv_th_k<<<dim3(NPIX / 128, BATCH), 256, 0, stream>>>(
        xT, th_wh, theta_b, theta_h, NPIX);

    mfma_conv_pg_k<<<dim3(MPIX / 128, BATCH, 2), 256, 0, stream>>>(
        xpT, ph_wh, phi_b, g_wh, g_b, phi_h, G_h);

    attn_v5<<<dim3(256), 512, 0, stream>>>(theta_h, phi_h, G_h, Z);

    conv_fin_k<<<dim3(16, 4, BATCH), 256, 0, stream>>>(Z, wz_wh, wz_b, x, out);
}